// Round 1
// baseline (10735.429 us; speedup 1.0000x reference)
//
#include <hip/hip_runtime.h>
#include <stdint.h>

#define GF_ACC   1
#define GF_BIAS  2
#define GF_BIAS0 4
#define GF_RELU  8

#define BM 64
#define BN 64
#define BK 16

// ---------------- CSR build ----------------

__global__ void deg_count_kernel(const int* __restrict__ src, const int* __restrict__ dst,
                                 const float* __restrict__ ew,
                                 float* __restrict__ deg, int* __restrict__ cnt, int E)
{
    int e = blockIdx.x * blockDim.x + threadIdx.x;
    if (e < E) {
        int d = dst[e];
        atomicAdd(&deg[d], ew[e]);
        atomicAdd(&cnt[d], 1);
    }
}

__global__ void dis_kernel(const float* __restrict__ deg, float* __restrict__ dis, int n)
{
    int i = blockIdx.x * blockDim.x + threadIdx.x;
    if (i < n) {
        float d = deg[i];
        dis[i] = (d > 0.f) ? (1.0f / sqrtf(d)) : 0.f;
    }
}

// single-block exclusive scan: cnt_cursor (in: counts, out: exclusive prefix = row start)
// row_ptr[i+1] = inclusive prefix; row_ptr[0] = 0
__global__ __launch_bounds__(1024) void scan_kernel(int* __restrict__ cnt_cursor,
                                                    int* __restrict__ row_ptr, int n)
{
    __shared__ int wsum[16];
    __shared__ int s_carry;
    if (threadIdx.x == 0) s_carry = 0;
    __syncthreads();
    const int VT = 8;
    const int CHUNK = 1024 * VT;
    int lane = threadIdx.x & 63;
    int wid = threadIdx.x >> 6;
    for (int base = 0; base < n; base += CHUNK) {
        int v[VT];
        int idx0 = base + threadIdx.x * VT;
        int tsum = 0;
#pragma unroll
        for (int t = 0; t < VT; t++) {
            int i = idx0 + t;
            v[t] = (i < n) ? cnt_cursor[i] : 0;
            tsum += v[t];
        }
        int incl = tsum;
        for (int off = 1; off < 64; off <<= 1) {
            int t = __shfl_up(incl, off);
            if (lane >= off) incl += t;
        }
        if (lane == 63) wsum[wid] = incl;
        __syncthreads();
        if (wid == 0) {
            int wv = (lane < 16) ? wsum[lane] : 0;
            for (int off = 1; off < 16; off <<= 1) {
                int t = __shfl_up(wv, off);
                if (lane >= off) wv += t;
            }
            if (lane < 16) wsum[lane] = wv;
        }
        __syncthreads();
        int wave_off = (wid > 0) ? wsum[wid - 1] : 0;
        int excl = incl - tsum + wave_off + s_carry;
#pragma unroll
        for (int t = 0; t < VT; t++) {
            int i = idx0 + t;
            if (i < n) {
                cnt_cursor[i] = excl;
                row_ptr[i + 1] = excl + v[t];
            }
            excl += v[t];
        }
        __syncthreads();
        if (threadIdx.x == 0) s_carry += wsum[15];
        __syncthreads();
    }
    if (threadIdx.x == 0) row_ptr[0] = 0;
}

__global__ void scatter_kernel(const int* __restrict__ src, const int* __restrict__ dst,
                               const float* __restrict__ ew, const float* __restrict__ dis,
                               int* __restrict__ cursor,
                               int* __restrict__ csr_s, float* __restrict__ csr_n, int E)
{
    int e = blockIdx.x * blockDim.x + threadIdx.x;
    if (e < E) {
        int s = src[e], d = dst[e];
        int pos = atomicAdd(&cursor[d], 1);
        csr_s[pos] = s;
        csr_n[pos] = dis[s] * ew[e] * dis[d];
    }
}

// ---------------- propagation ----------------

// one wave per dst node, lanes strided over C columns (C <= 256)
__global__ __launch_bounds__(256) void prop_wide(const float* __restrict__ X, float* __restrict__ Y,
                                                 const int* __restrict__ rp, const int* __restrict__ cs,
                                                 const float* __restrict__ cn, int C, int n)
{
    int node = blockIdx.x * 4 + (threadIdx.x >> 6);
    if (node >= n) return;
    int lane = threadIdx.x & 63;
    int e0 = rp[node], e1 = rp[node + 1];
    float a0 = 0.f, a1 = 0.f, a2 = 0.f, a3 = 0.f;
    for (int eb = e0; eb < e1; eb += 64) {
        int ne = min(64, e1 - eb);
        int s = 0; float w = 0.f;
        if (lane < ne) { s = cs[eb + lane]; w = cn[eb + lane]; }
        for (int j = 0; j < ne; j++) {
            int sj = __shfl(s, j);
            float wj = __shfl(w, j);
            const float* xr = X + sj * C;
            if (lane < C)        a0 += wj * xr[lane];
            if (lane + 64 < C)   a1 += wj * xr[lane + 64];
            if (lane + 128 < C)  a2 += wj * xr[lane + 128];
            if (lane + 192 < C)  a3 += wj * xr[lane + 192];
        }
    }
    float* yr = Y + node * C;
    if (lane < C)        yr[lane] = a0;
    if (lane + 64 < C)   yr[lane + 64] = a1;
    if (lane + 128 < C)  yr[lane + 128] = a2;
    if (lane + 192 < C)  yr[lane + 192] = a3;
}

// width-1 propagation: y[i] = (z? z[i]:0) + sum_e norm*x[src]; mode 1 = sigmoid epilogue
__global__ void prop1(const float* __restrict__ xv, const float* __restrict__ z,
                      float* __restrict__ y, const int* __restrict__ rp,
                      const int* __restrict__ cs, const float* __restrict__ cn,
                      int n, int mode)
{
    int i = blockIdx.x * blockDim.x + threadIdx.x;
    if (i >= n) return;
    float acc = (z != nullptr) ? z[i] : 0.f;
    int e1 = rp[i + 1];
    for (int e = rp[i]; e < e1; e++) acc += cn[e] * xv[cs[e]];
    if (mode == 1) acc = 1.0f / (1.0f + expf(-acc));
    y[i] = acc;
}

// ---------------- GEMM ----------------
// out[m,c] (+)= sum_k X[m,k]*W[k,c]  with generic strides; optional bias/relu.
__global__ __launch_bounds__(256) void gemm_kernel(
    const float* __restrict__ X, int x_sn, int x_sk,
    const float* __restrict__ W, int w_sk, int w_sc,
    const float* __restrict__ bias,
    float* __restrict__ out, int o_sn, int o_sc,
    int M, int K, int NC, int flags)
{
    __shared__ float Xs[BK][BM + 4];
    __shared__ float Ws[BK][BN];
    int tid = threadIdx.x;
    int bm = blockIdx.x * BM;
    int bn = blockIdx.y * BN;
    int tx = tid & 15;
    int ty = tid >> 4;
    float acc[4][4] = {};
    int kk_l = tid & 15, m_l = tid >> 4;
    int co_l = tid & 63, kr_l = tid >> 6;
    for (int k0 = 0; k0 < K; k0 += BK) {
#pragma unroll
        for (int r = 0; r < 4; r++) {
            int m = m_l + 16 * r;
            int gm = bm + m, gk = k0 + kk_l;
            Xs[kk_l][m] = (gm < M && gk < K) ? X[gm * x_sn + gk * x_sk] : 0.f;
        }
#pragma unroll
        for (int r = 0; r < 4; r++) {
            int kk = kr_l + 4 * r;
            int gk = k0 + kk, gc = bn + co_l;
            Ws[kk][co_l] = (gk < K && gc < NC) ? W[gk * w_sk + gc * w_sc] : 0.f;
        }
        __syncthreads();
#pragma unroll
        for (int kk = 0; kk < BK; kk++) {
            float xv[4], wv[4];
#pragma unroll
            for (int i = 0; i < 4; i++) xv[i] = Xs[kk][ty * 4 + i];
#pragma unroll
            for (int j = 0; j < 4; j++) wv[j] = Ws[kk][tx * 4 + j];
#pragma unroll
            for (int i = 0; i < 4; i++)
#pragma unroll
                for (int j = 0; j < 4; j++)
                    acc[i][j] += xv[i] * wv[j];
        }
        __syncthreads();
    }
#pragma unroll
    for (int i = 0; i < 4; i++) {
        int gm = bm + ty * 4 + i;
        if (gm >= M) continue;
#pragma unroll
        for (int j = 0; j < 4; j++) {
            int gc = bn + tx * 4 + j;
            if (gc >= NC) continue;
            int oi = gm * o_sn + gc * o_sc;
            float v = acc[i][j];
            if (flags & GF_ACC)  v += out[oi];
            if (flags & GF_BIAS) v += bias[gc];
            if (flags & GF_BIAS0) { if (gc == 0) v += bias[0]; }
            if (flags & GF_RELU) v = fmaxf(v, 0.f);
            out[oi] = v;
        }
    }
}

// ---------------- launch ----------------

extern "C" void kernel_launch(void* const* d_in, const int* in_sizes, int n_in,
                              void* d_out, int out_size, void* d_ws, size_t ws_size,
                              hipStream_t stream)
{
    const int N = 50000, E = 800000, K = 20;
    const float* x  = (const float*)d_in[0];
    const int*   ei = (const int*)d_in[1];
    const float* ew = (const float*)d_in[2];
    const float* Wl[5]; const float* bl[5];
    for (int l = 0; l < 5; l++) { Wl[l] = (const float*)d_in[3 + 2 * l]; bl[l] = (const float*)d_in[4 + 2 * l]; }
    const int* src = ei;
    const int* dst = ei + E;

    char* p = (char*)d_ws;
    auto alloc = [&](size_t bytes) -> char* {
        char* q = (char*)(((uintptr_t)p + 255) & ~(uintptr_t)255);
        p = q + bytes;
        return q;
    };
    float* deg    = (float*)alloc((size_t)N * 4);
    float* dis    = (float*)alloc((size_t)N * 4);
    int*   rowptr = (int*)alloc((size_t)(N + 1) * 4);
    int*   cursor = (int*)alloc((size_t)N * 4);
    int*   csr_s  = (int*)alloc((size_t)E * 4);
    float* csr_n  = (float*)alloc((size_t)E * 4);
    float* Zb     = (float*)alloc((size_t)(K + 1) * N * 4);
    float* ya     = (float*)alloc((size_t)N * 4);
    float* yb     = (float*)alloc((size_t)N * 4);
    float* buf0   = (float*)alloc((size_t)N * 200 * 4);
    float* buf1   = (float*)alloc((size_t)N * 200 * 4);
    float* buf2   = (float*)alloc((size_t)N * 200 * 4);
    (void)ws_size; (void)in_sizes; (void)n_in; (void)out_size;

    hipMemsetAsync(deg, 0, (size_t)N * 4, stream);
    hipMemsetAsync(cursor, 0, (size_t)N * 4, stream);
    deg_count_kernel<<<(E + 255) / 256, 256, 0, stream>>>(src, dst, ew, deg, cursor, E);
    dis_kernel<<<(N + 255) / 256, 256, 0, stream>>>(deg, dis, N);
    scan_kernel<<<1, 1024, 0, stream>>>(cursor, rowptr, N);
    scatter_kernel<<<(E + 255) / 256, 256, 0, stream>>>(src, dst, ew, dis, cursor, csr_s, csr_n, E);

    // ---- Layer 1 (1 -> 60): width-1 chain, then one batched GEMM over k
    hipMemcpyAsync(Zb, x, (size_t)N * 4, hipMemcpyDeviceToDevice, stream);
    for (int k = 1; k <= K; k++)
        prop1<<<(N + 255) / 256, 256, 0, stream>>>(Zb + (size_t)(k - 1) * N, nullptr, Zb + (size_t)k * N,
                                                   rowptr, csr_s, csr_n, N, 0);
    {
        dim3 g((N + BM - 1) / BM, (60 + BN - 1) / BN);
        gemm_kernel<<<g, 256, 0, stream>>>(Zb, 1, N, Wl[0], 60, 1, bl[0],
                                           buf0, 60, 1, N, K + 1, 60, GF_BIAS | GF_RELU);
    }

    // ---- middle layers: per-hop prop (width Cin) + accumulating GEMM
    auto middle = [&](const float* Wt, const float* bt, int Cin, int Cout,
                      float* X0, float* Xalt, float* Out) {
        dim3 g((N + BM - 1) / BM, (Cout + BN - 1) / BN);
        gemm_kernel<<<g, 256, 0, stream>>>(X0, Cin, 1, Wt, Cout, 1, bt,
                                           Out, Cout, 1, N, Cin, Cout, GF_BIAS);
        float* cur = X0; float* nxt = Xalt;
        for (int k = 1; k <= K; k++) {
            prop_wide<<<(N + 3) / 4, 256, 0, stream>>>(cur, nxt, rowptr, csr_s, csr_n, Cin, N);
            int fl = GF_ACC | (k == K ? GF_RELU : 0);
            gemm_kernel<<<g, 256, 0, stream>>>(nxt, Cin, 1, Wt + (size_t)k * Cin * Cout, Cout, 1, bt,
                                               Out, Cout, 1, N, Cin, Cout, fl);
            float* t = cur; cur = nxt; nxt = t;
        }
    };
    middle(Wl[1], bl[1], 60, 100, buf0, buf1, buf2);   // L2: out in buf2
    middle(Wl[2], bl[2], 100, 200, buf2, buf0, buf1);  // L3: out in buf1
    middle(Wl[3], bl[3], 200, 80, buf1, buf2, buf0);   // L4: out in buf0

    // ---- Layer 5 (80 -> 1): Z[k] = X@W5[k] (+b at k=0); Horner in width-1 space
    {
        dim3 g((N + BM - 1) / BM, (K + 1 + BN - 1) / BN);
        gemm_kernel<<<g, 256, 0, stream>>>(buf0, 80, 1, Wl[4], 1, 80, bl[4],
                                           Zb, 1, N, N, 80, K + 1, GF_BIAS0);
    }
    float* cur = Zb + (size_t)K * N;
    float* outp = (float*)d_out;
    for (int k = K - 1; k >= 0; k--) {
        float* nxt = (k == 0) ? outp : ((k & 1) ? ya : yb);
        prop1<<<(N + 255) / 256, 256, 0, stream>>>(cur, Zb + (size_t)k * N, nxt,
                                                   rowptr, csr_s, csr_n, N, (k == 0) ? 1 : 0);
        cur = nxt;
    }
}

// Round 2
// 7067.956 us; speedup vs baseline: 1.5189x; 1.5189x over previous
//
#include <hip/hip_runtime.h>
#include <stdint.h>

#define GF_ACC   1
#define GF_BIAS  2
#define GF_RELU  8

#define BM 128
#define BN 64
#define BK 16

// ---------------- CSR build ----------------

__global__ void deg_count_kernel(const int* __restrict__ src, const int* __restrict__ dst,
                                 const float* __restrict__ ew,
                                 float* __restrict__ deg, int* __restrict__ cnt, int E)
{
    int e = blockIdx.x * blockDim.x + threadIdx.x;
    if (e < E) {
        int d = dst[e];
        atomicAdd(&deg[d], ew[e]);
        atomicAdd(&cnt[d], 1);
    }
}

__global__ void dis_kernel(const float* __restrict__ deg, float* __restrict__ dis, int n)
{
    int i = blockIdx.x * blockDim.x + threadIdx.x;
    if (i < n) {
        float d = deg[i];
        dis[i] = (d > 0.f) ? (1.0f / sqrtf(d)) : 0.f;
    }
}

__global__ __launch_bounds__(1024) void scan_kernel(int* __restrict__ cnt_cursor,
                                                    int* __restrict__ row_ptr, int n)
{
    __shared__ int wsum[16];
    __shared__ int s_carry;
    if (threadIdx.x == 0) s_carry = 0;
    __syncthreads();
    const int VT = 8;
    const int CHUNK = 1024 * VT;
    int lane = threadIdx.x & 63;
    int wid = threadIdx.x >> 6;
    for (int base = 0; base < n; base += CHUNK) {
        int v[VT];
        int idx0 = base + threadIdx.x * VT;
        int tsum = 0;
#pragma unroll
        for (int t = 0; t < VT; t++) {
            int i = idx0 + t;
            v[t] = (i < n) ? cnt_cursor[i] : 0;
            tsum += v[t];
        }
        int incl = tsum;
        for (int off = 1; off < 64; off <<= 1) {
            int t = __shfl_up(incl, off);
            if (lane >= off) incl += t;
        }
        if (lane == 63) wsum[wid] = incl;
        __syncthreads();
        if (wid == 0) {
            int wv = (lane < 16) ? wsum[lane] : 0;
            for (int off = 1; off < 16; off <<= 1) {
                int t = __shfl_up(wv, off);
                if (lane >= off) wv += t;
            }
            if (lane < 16) wsum[lane] = wv;
        }
        __syncthreads();
        int wave_off = (wid > 0) ? wsum[wid - 1] : 0;
        int excl = incl - tsum + wave_off + s_carry;
#pragma unroll
        for (int t = 0; t < VT; t++) {
            int i = idx0 + t;
            if (i < n) {
                cnt_cursor[i] = excl;
                row_ptr[i + 1] = excl + v[t];
            }
            excl += v[t];
        }
        __syncthreads();
        if (threadIdx.x == 0) s_carry += wsum[15];
        __syncthreads();
    }
    if (threadIdx.x == 0) row_ptr[0] = 0;
}

__global__ void scatter_kernel(const int* __restrict__ src, const int* __restrict__ dst,
                               const float* __restrict__ ew, const float* __restrict__ dis,
                               int* __restrict__ cursor,
                               int* __restrict__ csr_s, float* __restrict__ csr_n, int E)
{
    int e = blockIdx.x * blockDim.x + threadIdx.x;
    if (e < E) {
        int s = src[e], d = dst[e];
        int pos = atomicAdd(&cursor[d], 1);
        csr_s[pos] = s;
        csr_n[pos] = dis[s] * ew[e] * dis[d];
    }
}

// ---------------- propagation ----------------

// width-1 propagation, 4 lanes per node: y[i] = (z? z[i]:0) + sum_e norm*x[src]
__global__ __launch_bounds__(256) void prop1(const float* __restrict__ xv, const float* __restrict__ z,
                                             float* __restrict__ y, const int* __restrict__ rp,
                                             const int* __restrict__ cs, const float* __restrict__ cn,
                                             int n, int mode)
{
    int node = blockIdx.x * 64 + (threadIdx.x >> 2);
    if (node >= n) return;
    int g = threadIdx.x & 3;
    int e0 = rp[node], e1 = rp[node + 1];
    float acc = 0.f;
    for (int e = e0 + g; e < e1; e += 4)
        acc += cn[e] * xv[cs[e]];
    acc += __shfl_xor(acc, 1);
    acc += __shfl_xor(acc, 2);
    if (g == 0) {
        if (z) acc += z[node];
        if (mode == 1) acc = 1.0f / (1.0f + expf(-acc));
        y[node] = acc;
    }
}

// wide propagation: wave per node; lane = (edge_sub, col4); float4 gathers, 4x edge unroll.
// Y[node] = A-gather(X) (+ Z[node]) (relu optional). Row strides in floats.
template<int C4, int EPW, bool HASZ, bool RELU>
__global__ __launch_bounds__(256) void propw(const float* __restrict__ X, int xstr,
                                             const float* __restrict__ Z, int zstr,
                                             float* __restrict__ Y, int ystr,
                                             const int* __restrict__ rp,
                                             const int* __restrict__ cs,
                                             const float* __restrict__ cn, int n)
{
    int node = blockIdx.x * 4 + (threadIdx.x >> 6);
    if (node >= n) return;
    int lane = threadIdx.x & 63;
    int c4 = lane % C4;
    int e_sub = lane / C4;
    bool active = (lane < C4 * EPW);
    int e0 = rp[node], e1 = rp[node + 1];
    float ax = 0.f, ay = 0.f, az = 0.f, aw = 0.f;
    for (int base = e0; base < e1; base += EPW * 4) {
        int sv[4]; float wv[4];
#pragma unroll
        for (int u = 0; u < 4; u++) {
            int eid = base + u * EPW + e_sub;
            bool ok = active && (eid < e1);
            sv[u] = ok ? cs[eid] : 0;
            wv[u] = ok ? cn[eid] : 0.f;
        }
        float4 xq[4];
#pragma unroll
        for (int u = 0; u < 4; u++)
            xq[u] = *(const float4*)(X + (size_t)sv[u] * xstr + 4 * c4);
#pragma unroll
        for (int u = 0; u < 4; u++) {
            ax += wv[u] * xq[u].x; ay += wv[u] * xq[u].y;
            az += wv[u] * xq[u].z; aw += wv[u] * xq[u].w;
        }
    }
    // reduce partials across the EPW edge groups onto lanes [0, C4)
    float ox = ax, oy = ay, oz = az, ow = aw;
#pragma unroll
    for (int g = 1; g < EPW; g++) {
        int sl = c4 + g * C4;
        ax += __shfl(ox, sl); ay += __shfl(oy, sl);
        az += __shfl(oz, sl); aw += __shfl(ow, sl);
    }
    if (lane < C4) {
        if (HASZ) {
            float4 zq = *(const float4*)(Z + (size_t)node * zstr + 4 * c4);
            ax += zq.x; ay += zq.y; az += zq.z; aw += zq.w;
        }
        if (RELU) {
            ax = fmaxf(ax, 0.f); ay = fmaxf(ay, 0.f);
            az = fmaxf(az, 0.f); aw = fmaxf(aw, 0.f);
        }
        float4 o = { ax, ay, az, aw };
        *(float4*)(Y + (size_t)node * ystr + 4 * c4) = o;
    }
}

// ---------------- GEMM ----------------
// out[m,c] (+)= sum_k X[m,k]*W[k,c], generic strides; bias applied to cols < bias_cols.
__global__ __launch_bounds__(256) void gemm2(
    const float* __restrict__ X, int x_sn, int x_sk,
    const float* __restrict__ W, int w_sk, int w_sc,
    const float* __restrict__ bias,
    float* __restrict__ out, int o_sn, int o_sc,
    int M, int K, int NC, int flags, int bias_cols)
{
    __shared__ float Xs[BK][BM + 4];   // stride 132 floats -> 16B aligned rows
    __shared__ float Ws[BK][BN];
    int tid = threadIdx.x;
    int bm = blockIdx.x * BM;
    int bn = blockIdx.y * BN;
    int tx = tid & 15;        // col group: 4 cols
    int ty = tid >> 4;        // row group: 8 rows
    float acc[8][4] = {};
    int xk = tid & 15, xm = tid >> 4;
    int wc = tid & 63, wk = tid >> 6;
    for (int k0 = 0; k0 < K; k0 += BK) {
#pragma unroll
        for (int r = 0; r < 8; r++) {
            int m = xm + 16 * r;
            int gm = bm + m, gk = k0 + xk;
            Xs[xk][m] = (gm < M && gk < K) ? X[(size_t)gm * x_sn + (size_t)gk * x_sk] : 0.f;
        }
#pragma unroll
        for (int r = 0; r < 4; r++) {
            int kk = wk + 4 * r;
            int gk = k0 + kk, gc = bn + wc;
            Ws[kk][wc] = (gk < K && gc < NC) ? W[(size_t)gk * w_sk + (size_t)gc * w_sc] : 0.f;
        }
        __syncthreads();
#pragma unroll
        for (int kk = 0; kk < BK; kk++) {
            float xv[8], wv[4];
#pragma unroll
            for (int i = 0; i < 8; i++) xv[i] = Xs[kk][ty * 8 + i];
#pragma unroll
            for (int j = 0; j < 4; j++) wv[j] = Ws[kk][tx * 4 + j];
#pragma unroll
            for (int i = 0; i < 8; i++)
#pragma unroll
                for (int j = 0; j < 4; j++)
                    acc[i][j] += xv[i] * wv[j];
        }
        __syncthreads();
    }
#pragma unroll
    for (int i = 0; i < 8; i++) {
        int gm = bm + ty * 8 + i;
        if (gm >= M) continue;
#pragma unroll
        for (int j = 0; j < 4; j++) {
            int gc = bn + tx * 4 + j;
            if (gc >= NC) continue;
            size_t oi = (size_t)gm * o_sn + (size_t)gc * o_sc;
            float v = acc[i][j];
            if (flags & GF_ACC)  v += out[oi];
            if ((flags & GF_BIAS) && gc < bias_cols) v += bias[gc];
            if (flags & GF_RELU) v = fmaxf(v, 0.f);
            out[oi] = v;
        }
    }
}

// W4 [21,200,80] -> W4t [200, 21*80] with col = hop*80+co
__global__ void w4t_kernel(const float* __restrict__ w, float* __restrict__ wt, int total)
{
    int t = blockIdx.x * blockDim.x + threadIdx.x;
    if (t >= total) return;
    int oc = t % 1680, cin = t / 1680;
    int hop = oc / 80, co = oc % 80;
    wt[t] = w[hop * 16000 + cin * 80 + co];
}

// ---------------- launch ----------------

extern "C" void kernel_launch(void* const* d_in, const int* in_sizes, int n_in,
                              void* d_out, int out_size, void* d_ws, size_t ws_size,
                              hipStream_t stream)
{
    const int N = 50000, E = 800000, K = 20;
    const float* x  = (const float*)d_in[0];
    const int*   ei = (const int*)d_in[1];
    const float* ew = (const float*)d_in[2];
    const float* Wl[5]; const float* bl[5];
    for (int l = 0; l < 5; l++) { Wl[l] = (const float*)d_in[3 + 2 * l]; bl[l] = (const float*)d_in[4 + 2 * l]; }
    const int* src = ei;
    const int* dst = ei + E;
    (void)in_sizes; (void)n_in; (void)out_size;

    uintptr_t base = (uintptr_t)d_ws;
    uintptr_t cur = base;
    auto alloc = [&](size_t bytes) -> char* {
        uintptr_t q = (cur + 255) & ~(uintptr_t)255;
        cur = q + bytes;
        return (char*)q;
    };
    float* deg    = (float*)alloc((size_t)N * 4);
    float* dis    = (float*)alloc((size_t)N * 4);
    int*   rowptr = (int*)alloc((size_t)(N + 1) * 4);
    int*   cursor = (int*)alloc((size_t)N * 4);
    int*   csr_s  = (int*)alloc((size_t)E * 4);
    float* csr_n  = (float*)alloc((size_t)E * 4);
    float* Zb     = (float*)alloc((size_t)(K + 1) * N * 4);  // [21, N] hop-major
    float* ya     = (float*)alloc((size_t)N * 4);
    float* yb     = (float*)alloc((size_t)N * 4);
    float* h1     = (float*)alloc((size_t)N * 60 * 4);
    float* h2     = (float*)alloc((size_t)N * 100 * 4);
    float* h3     = (float*)alloc((size_t)N * 200 * 4);
    float* h4     = (float*)alloc((size_t)N * 80 * 4);
    float* Ra     = (float*)alloc((size_t)N * 80 * 4);
    float* Rb     = (float*)alloc((size_t)N * 80 * 4);
    float* W4t    = (float*)alloc((size_t)200 * 1680 * 4);

    const size_t ARENA_BYTES = (size_t)N * 20 * 100 * 4;  // 400 MB: S2/S3/Z4 sequentially
    bool fat = ((size_t)(cur - base) + ARENA_BYTES + 65536 <= ws_size);

    float* arena = nullptr; float* P0 = nullptr; float* P1 = nullptr; float* Zt = nullptr;
    if (fat) {
        arena = (float*)alloc(ARENA_BYTES);
    } else {
        P0 = (float*)alloc((size_t)N * 100 * 4);
        P1 = (float*)alloc((size_t)N * 100 * 4);
        Zt = (float*)alloc((size_t)N * 80 * 4);
    }

    // ---- CSR build
    hipMemsetAsync(deg, 0, (size_t)N * 4, stream);
    hipMemsetAsync(cursor, 0, (size_t)N * 4, stream);
    deg_count_kernel<<<(E + 255) / 256, 256, 0, stream>>>(src, dst, ew, deg, cursor, E);
    dis_kernel<<<(N + 255) / 256, 256, 0, stream>>>(deg, dis, N);
    scan_kernel<<<1, 1024, 0, stream>>>(cursor, rowptr, N);
    scatter_kernel<<<(E + 255) / 256, 256, 0, stream>>>(src, dst, ew, dis, cursor, csr_s, csr_n, E);

    const int PB = (N + 63) / 64;    // prop1 blocks
    const int WB = (N + 3) / 4;      // propw blocks
    const int GMX = (N + BM - 1) / BM;

    // ---- Layer 1 (1 -> 60): width-1 chain into Zb, one GEMM K=21
    hipMemcpyAsync(Zb, x, (size_t)N * 4, hipMemcpyDeviceToDevice, stream);
    for (int k = 1; k <= K; k++)
        prop1<<<PB, 256, 0, stream>>>(Zb + (size_t)(k - 1) * N, nullptr, Zb + (size_t)k * N,
                                      rowptr, csr_s, csr_n, N, 0);
    gemm2<<<dim3(GMX, 1), 256, 0, stream>>>(Zb, 1, N, Wl[0], 60, 1, bl[0],
                                            h1, 60, 1, N, K + 1, 60, GF_BIAS | GF_RELU, 60);

    if (fat) {
        // ---- Layer 2 (60 -> 100): forward props into stack S2 [N,20,60], 2-pass GEMM
        float* S = arena;
        for (int k = 1; k <= K; k++) {
            const float* xin = (k == 1) ? h1 : (S + (size_t)(k - 2) * 60);
            int xs = (k == 1) ? 60 : 1200;
            propw<15, 4, false, false><<<WB, 256, 0, stream>>>(xin, xs, nullptr, 0,
                S + (size_t)(k - 1) * 60, 1200, rowptr, csr_s, csr_n, N);
        }
        gemm2<<<dim3(GMX, 2), 256, 0, stream>>>(h1, 60, 1, Wl[1], 100, 1, bl[1],
                                                h2, 100, 1, N, 60, 100, GF_BIAS, 100);
        gemm2<<<dim3(GMX, 2), 256, 0, stream>>>(S, 1200, 1, Wl[1] + 6000, 100, 1, nullptr,
                                                h2, 100, 1, N, 1200, 100, GF_ACC | GF_RELU, 0);

        // ---- Layer 3 (100 -> 200): forward props into S3 [N,20,100], 2-pass GEMM
        for (int k = 1; k <= K; k++) {
            const float* xin = (k == 1) ? h2 : (S + (size_t)(k - 2) * 100);
            int xs = (k == 1) ? 100 : 2000;
            propw<25, 2, false, false><<<WB, 256, 0, stream>>>(xin, xs, nullptr, 0,
                S + (size_t)(k - 1) * 100, 2000, rowptr, csr_s, csr_n, N);
        }
        gemm2<<<dim3(GMX, 4), 256, 0, stream>>>(h2, 100, 1, Wl[2], 200, 1, bl[2],
                                                h3, 200, 1, N, 100, 200, GF_BIAS, 200);
        gemm2<<<dim3(GMX, 4), 256, 0, stream>>>(S, 2000, 1, Wl[2] + 20000, 200, 1, nullptr,
                                                h3, 200, 1, N, 2000, 200, GF_ACC | GF_RELU, 0);

        // ---- Layer 4 (200 -> 80): pre-GEMM all Z_k = h3@W4[k] (bias on hop 0), Horner width-80
        float* Z4 = arena;  // [N, 21*80] = 336 MB (S3 dead)
        w4t_kernel<<<(336000 + 255) / 256, 256, 0, stream>>>(Wl[3], W4t, 336000);
        gemm2<<<dim3(GMX, 27), 256, 0, stream>>>(h3, 200, 1, W4t, 1680, 1, bl[3],
                                                 Z4, 1680, 1, N, 200, 1680, GF_BIAS, 80);
        const float* cur4 = Z4 + (size_t)K * 80; int cstr = 1680;
        for (int k = K - 1; k >= 0; k--) {
            if (k == 0) {
                propw<20, 3, true, true><<<WB, 256, 0, stream>>>(cur4, cstr, Z4 + (size_t)k * 80, 1680,
                    h4, 80, rowptr, csr_s, csr_n, N);
            } else {
                float* o = (k & 1) ? Ra : Rb;
                propw<20, 3, true, false><<<WB, 256, 0, stream>>>(cur4, cstr, Z4 + (size_t)k * 80, 1680,
                    o, 80, rowptr, csr_s, csr_n, N);
                cur4 = o; cstr = 80;
            }
        }
    } else {
        // ---- slim fallback: per-hop accumulate GEMMs
        // L2 forward
        gemm2<<<dim3(GMX, 2), 256, 0, stream>>>(h1, 60, 1, Wl[1], 100, 1, bl[1],
                                                h2, 100, 1, N, 60, 100, GF_BIAS, 100);
        {
            const float* curp = h1;
            for (int k = 1; k <= K; k++) {
                float* nx = (k & 1) ? P0 : P1;
                propw<15, 4, false, false><<<WB, 256, 0, stream>>>(curp, 60, nullptr, 0,
                    nx, 60, rowptr, csr_s, csr_n, N);
                gemm2<<<dim3(GMX, 2), 256, 0, stream>>>(nx, 60, 1, Wl[1] + (size_t)k * 6000, 100, 1, nullptr,
                                                        h2, 100, 1, N, 60, 100,
                                                        GF_ACC | (k == K ? GF_RELU : 0), 0);
                curp = nx;
            }
        }
        // L3 forward
        gemm2<<<dim3(GMX, 4), 256, 0, stream>>>(h2, 100, 1, Wl[2], 200, 1, bl[2],
                                                h3, 200, 1, N, 100, 200, GF_BIAS, 200);
        {
            const float* curp = h2;
            for (int k = 1; k <= K; k++) {
                float* nx = (k & 1) ? P0 : P1;
                propw<25, 2, false, false><<<WB, 256, 0, stream>>>(curp, 100, nullptr, 0,
                    nx, 100, rowptr, csr_s, csr_n, N);
                gemm2<<<dim3(GMX, 4), 256, 0, stream>>>(nx, 100, 1, Wl[2] + (size_t)k * 20000, 200, 1, nullptr,
                                                        h3, 200, 1, N, 100, 200,
                                                        GF_ACC | (k == K ? GF_RELU : 0), 0);
                curp = nx;
            }
        }
        // L4 Horner: per-hop Z_k GEMM + fused prop-add
        gemm2<<<dim3(GMX, 2), 256, 0, stream>>>(h3, 200, 1, Wl[3] + (size_t)K * 16000, 80, 1, nullptr,
                                                Ra, 80, 1, N, 200, 80, 0, 0);
        const float* cur4 = Ra;
        for (int k = K - 1; k >= 0; k--) {
            gemm2<<<dim3(GMX, 2), 256, 0, stream>>>(h3, 200, 1, Wl[3] + (size_t)k * 16000, 80, 1, bl[3],
                                                    Zt, 80, 1, N, 200, 80,
                                                    (k == 0 ? GF_BIAS : 0), 80);
            if (k == 0) {
                propw<20, 3, true, true><<<WB, 256, 0, stream>>>(cur4, 80, Zt, 80,
                    h4, 80, rowptr, csr_s, csr_n, N);
            } else {
                float* o = (k & 1) ? Rb : Ra;
                propw<20, 3, true, false><<<WB, 256, 0, stream>>>(cur4, 80, Zt, 80,
                    o, 80, rowptr, csr_s, csr_n, N);
                cur4 = o;
            }
        }
    }

    // ---- Layer 5 (80 -> 1): pre-GEMM Z5 [21, N] col-major, Horner width-1 with sigmoid
    gemm2<<<dim3(GMX, 1), 256, 0, stream>>>(h4, 80, 1, Wl[4], 1, 80, bl[4],
                                            Zb, 1, N, N, 80, K + 1, GF_BIAS, 1);
    const float* cur5 = Zb + (size_t)K * N;
    float* outp = (float*)d_out;
    for (int k = K - 1; k >= 0; k--) {
        float* o = (k == 0) ? outp : ((k & 1) ? ya : yb);
        prop1<<<PB, 256, 0, stream>>>(cur5, Zb + (size_t)k * N, o,
                                      rowptr, csr_s, csr_n, N, (k == 0) ? 1 : 0);
        cur5 = o;
    }
}

// Round 3
// 5273.805 us; speedup vs baseline: 2.0356x; 1.3402x over previous
//
#include <hip/hip_runtime.h>
#include <stdint.h>

#define GF_ACC   1
#define GF_BIAS  2
#define GF_RELU  8

#define BM 128
#define BN 64
#define BK 16

// ---------------- CSR build ----------------

__global__ void deg_count_kernel(const int* __restrict__ src, const int* __restrict__ dst,
                                 const float* __restrict__ ew,
                                 float* __restrict__ deg, int* __restrict__ cnt, int E)
{
    int e = blockIdx.x * blockDim.x + threadIdx.x;
    if (e < E) {
        int d = dst[e];
        atomicAdd(&deg[d], ew[e]);
        atomicAdd(&cnt[d], 1);
    }
}

__global__ void dis_kernel(const float* __restrict__ deg, float* __restrict__ dis, int n)
{
    int i = blockIdx.x * blockDim.x + threadIdx.x;
    if (i < n) {
        float d = deg[i];
        dis[i] = (d > 0.f) ? (1.0f / sqrtf(d)) : 0.f;
    }
}

__global__ __launch_bounds__(1024) void scan_kernel(int* __restrict__ cnt_cursor,
                                                    int* __restrict__ row_ptr, int n)
{
    __shared__ int wsum[16];
    __shared__ int s_carry;
    if (threadIdx.x == 0) s_carry = 0;
    __syncthreads();
    const int VT = 8;
    const int CHUNK = 1024 * VT;
    int lane = threadIdx.x & 63;
    int wid = threadIdx.x >> 6;
    for (int base = 0; base < n; base += CHUNK) {
        int v[VT];
        int idx0 = base + threadIdx.x * VT;
        int tsum = 0;
#pragma unroll
        for (int t = 0; t < VT; t++) {
            int i = idx0 + t;
            v[t] = (i < n) ? cnt_cursor[i] : 0;
            tsum += v[t];
        }
        int incl = tsum;
        for (int off = 1; off < 64; off <<= 1) {
            int t = __shfl_up(incl, off);
            if (lane >= off) incl += t;
        }
        if (lane == 63) wsum[wid] = incl;
        __syncthreads();
        if (wid == 0) {
            int wv = (lane < 16) ? wsum[lane] : 0;
            for (int off = 1; off < 16; off <<= 1) {
                int t = __shfl_up(wv, off);
                if (lane >= off) wv += t;
            }
            if (lane < 16) wsum[lane] = wv;
        }
        __syncthreads();
        int wave_off = (wid > 0) ? wsum[wid - 1] : 0;
        int excl = incl - tsum + wave_off + s_carry;
#pragma unroll
        for (int t = 0; t < VT; t++) {
            int i = idx0 + t;
            if (i < n) {
                cnt_cursor[i] = excl;
                row_ptr[i + 1] = excl + v[t];
            }
            excl += v[t];
        }
        __syncthreads();
        if (threadIdx.x == 0) s_carry += wsum[15];
        __syncthreads();
    }
    if (threadIdx.x == 0) row_ptr[0] = 0;
}

__global__ void scatter_kernel(const int* __restrict__ src, const int* __restrict__ dst,
                               const float* __restrict__ ew, const float* __restrict__ dis,
                               int* __restrict__ cursor,
                               int* __restrict__ csr_s, float* __restrict__ csr_n, int E)
{
    int e = blockIdx.x * blockDim.x + threadIdx.x;
    if (e < E) {
        int s = src[e], d = dst[e];
        int pos = atomicAdd(&cursor[d], 1);
        csr_s[pos] = s;
        csr_n[pos] = dis[s] * ew[e] * dis[d];
    }
}

// ---------------- propagation ----------------

__global__ __launch_bounds__(256) void prop1(const float* __restrict__ xv, const float* __restrict__ z,
                                             float* __restrict__ y, const int* __restrict__ rp,
                                             const int* __restrict__ cs, const float* __restrict__ cn,
                                             int n, int mode)
{
    int node = blockIdx.x * 64 + (threadIdx.x >> 2);
    if (node >= n) return;
    int g = threadIdx.x & 3;
    int e0 = rp[node], e1 = rp[node + 1];
    float acc = 0.f;
    for (int e = e0 + g; e < e1; e += 4)
        acc += cn[e] * xv[cs[e]];
    acc += __shfl_xor(acc, 1);
    acc += __shfl_xor(acc, 2);
    if (g == 0) {
        if (z) acc += z[node];
        if (mode == 1) acc = 1.0f / (1.0f + expf(-acc));
        y[node] = acc;
    }
}

// wide propagation: wave per node; lane = (edge_sub, col4); float4 gathers, 4x edge unroll.
template<int C4, int EPW, bool HASZ, bool RELU>
__global__ __launch_bounds__(256) void propw(const float* __restrict__ X, int xstr,
                                             const float* __restrict__ Z, int zstr,
                                             float* __restrict__ Y, int ystr,
                                             const int* __restrict__ rp,
                                             const int* __restrict__ cs,
                                             const float* __restrict__ cn, int n)
{
    int node = blockIdx.x * 4 + (threadIdx.x >> 6);
    if (node >= n) return;
    int lane = threadIdx.x & 63;
    int c4 = lane % C4;
    int e_sub = lane / C4;
    bool active = (lane < C4 * EPW);
    int e0 = rp[node], e1 = rp[node + 1];
    float ax = 0.f, ay = 0.f, az = 0.f, aw = 0.f;
    for (int base = e0; base < e1; base += EPW * 4) {
        int sv[4]; float wv[4];
#pragma unroll
        for (int u = 0; u < 4; u++) {
            int eid = base + u * EPW + e_sub;
            bool ok = active && (eid < e1);
            sv[u] = ok ? cs[eid] : 0;
            wv[u] = ok ? cn[eid] : 0.f;
        }
        float4 xq[4];
#pragma unroll
        for (int u = 0; u < 4; u++)
            xq[u] = *(const float4*)(X + (size_t)sv[u] * xstr + 4 * c4);
#pragma unroll
        for (int u = 0; u < 4; u++) {
            ax += wv[u] * xq[u].x; ay += wv[u] * xq[u].y;
            az += wv[u] * xq[u].z; aw += wv[u] * xq[u].w;
        }
    }
    float ox = ax, oy = ay, oz = az, ow = aw;
#pragma unroll
    for (int g = 1; g < EPW; g++) {
        int sl = c4 + g * C4;
        ax += __shfl(ox, sl); ay += __shfl(oy, sl);
        az += __shfl(oz, sl); aw += __shfl(ow, sl);
    }
    if (lane < C4) {
        if (HASZ) {
            float4 zq = *(const float4*)(Z + (size_t)node * zstr + 4 * c4);
            ax += zq.x; ay += zq.y; az += zq.z; aw += zq.w;
        }
        if (RELU) {
            ax = fmaxf(ax, 0.f); ay = fmaxf(ay, 0.f);
            az = fmaxf(az, 0.f); aw = fmaxf(aw, 0.f);
        }
        float4 o = { ax, ay, az, aw };
        *(float4*)(Y + (size_t)node * ystr + 4 * c4) = o;
    }
}

// ---------------- GEMM ----------------
// out[m,c] (+)= sum_k X[m,k]*W[k,c], generic strides; bias on cols < bias_cols.
// float4 fast paths when the inner strides are 1 and rows are 16B-aligned.
__global__ __launch_bounds__(256) void gemm2(
    const float* __restrict__ X, int x_sn, int x_sk,
    const float* __restrict__ W, int w_sk, int w_sc,
    const float* __restrict__ bias,
    float* __restrict__ out, int o_sn, int o_sc,
    int M, int K, int NC, int flags, int bias_cols)
{
    __shared__ float Xs[BK][BM + 4];
    __shared__ float Ws[BK][BN];
    int tid = threadIdx.x;
    int bm = blockIdx.x * BM;
    int bn = blockIdx.y * BN;
    int tx = tid & 15, ty = tid >> 4;
    float acc[8][4] = {};
    int xk = tid & 15, xm = tid >> 4;
    int wc = tid & 63, wk4 = tid >> 6;
    int vr = tid >> 2;            // 0..63
    int vc = (tid & 3) * 4;       // 0,4,8,12
    int wvk = tid >> 4;           // 0..15
    int wvc = (tid & 15) * 4;     // col offset
    bool xvec = (x_sk == 1) && ((x_sn & 3) == 0) && (bm + BM <= M);
    bool wvec = (w_sc == 1) && ((w_sk & 3) == 0) && (bn + BN <= NC);
    for (int k0 = 0; k0 < K; k0 += BK) {
        bool fullk = (k0 + BK <= K);
        if (xvec && fullk) {
#pragma unroll
            for (int h = 0; h < 2; h++) {
                int m = vr + 64 * h;
                const float4 q = *(const float4*)(X + (size_t)(bm + m) * x_sn + k0 + vc);
                Xs[vc + 0][m] = q.x; Xs[vc + 1][m] = q.y;
                Xs[vc + 2][m] = q.z; Xs[vc + 3][m] = q.w;
            }
        } else {
#pragma unroll
            for (int r = 0; r < 8; r++) {
                int m = xm + 16 * r;
                int gm = bm + m, gk = k0 + xk;
                Xs[xk][m] = (gm < M && gk < K) ? X[(size_t)gm * x_sn + (size_t)gk * x_sk] : 0.f;
            }
        }
        if (wvec && fullk) {
            *(float4*)&Ws[wvk][wvc] = *(const float4*)(W + (size_t)(k0 + wvk) * w_sk + bn + wvc);
        } else {
#pragma unroll
            for (int r = 0; r < 4; r++) {
                int kk = wk4 + 4 * r;
                int gk = k0 + kk, gc = bn + wc;
                Ws[kk][wc] = (gk < K && gc < NC) ? W[(size_t)gk * w_sk + (size_t)gc * w_sc] : 0.f;
            }
        }
        __syncthreads();
#pragma unroll
        for (int kk = 0; kk < BK; kk++) {
            float xv[8], wv[4];
#pragma unroll
            for (int i = 0; i < 8; i++) xv[i] = Xs[kk][ty * 8 + i];
#pragma unroll
            for (int j = 0; j < 4; j++) wv[j] = Ws[kk][tx * 4 + j];
#pragma unroll
            for (int i = 0; i < 8; i++)
#pragma unroll
                for (int j = 0; j < 4; j++)
                    acc[i][j] += xv[i] * wv[j];
        }
        __syncthreads();
    }
    bool ovec = (o_sc == 1) && ((o_sn & 3) == 0) && (bn + tx * 4 + 3 < NC);
#pragma unroll
    for (int i = 0; i < 8; i++) {
        int gm = bm + ty * 8 + i;
        if (gm >= M) continue;
        if (ovec) {
            float* op = out + (size_t)gm * o_sn + bn + tx * 4;
            float4 v = { acc[i][0], acc[i][1], acc[i][2], acc[i][3] };
            if (flags & GF_ACC) {
                float4 o = *(const float4*)op;
                v.x += o.x; v.y += o.y; v.z += o.z; v.w += o.w;
            }
            if (flags & GF_BIAS) {
#pragma unroll
                for (int j = 0; j < 4; j++) {
                    int gc = bn + tx * 4 + j;
                    if (gc < bias_cols) (&v.x)[j] += bias[gc];
                }
            }
            if (flags & GF_RELU) {
                v.x = fmaxf(v.x, 0.f); v.y = fmaxf(v.y, 0.f);
                v.z = fmaxf(v.z, 0.f); v.w = fmaxf(v.w, 0.f);
            }
            *(float4*)op = v;
        } else {
#pragma unroll
            for (int j = 0; j < 4; j++) {
                int gc = bn + tx * 4 + j;
                if (gc >= NC) continue;
                size_t oi = (size_t)gm * o_sn + (size_t)gc * o_sc;
                float v = acc[i][j];
                if (flags & GF_ACC)  v += out[oi];
                if ((flags & GF_BIAS) && gc < bias_cols) v += bias[gc];
                if (flags & GF_RELU) v = fmaxf(v, 0.f);
                out[oi] = v;
            }
        }
    }
}

// W4 [21,200,80] -> W4t [200, 21*80] with col = hop*80+co
__global__ void w4t_kernel(const float* __restrict__ w, float* __restrict__ wt, int total)
{
    int t = blockIdx.x * blockDim.x + threadIdx.x;
    if (t >= total) return;
    int oc = t % 1680, cin = t / 1680;
    int hop = oc / 80, co = oc % 80;
    wt[t] = w[hop * 16000 + cin * 80 + co];
}

// ---------------- launch ----------------

extern "C" void kernel_launch(void* const* d_in, const int* in_sizes, int n_in,
                              void* d_out, int out_size, void* d_ws, size_t ws_size,
                              hipStream_t stream)
{
    const int N = 50000, E = 800000, K = 20;
    const float* x  = (const float*)d_in[0];
    const int*   ei = (const int*)d_in[1];
    const float* ew = (const float*)d_in[2];
    const float* Wl[5]; const float* bl[5];
    for (int l = 0; l < 5; l++) { Wl[l] = (const float*)d_in[3 + 2 * l]; bl[l] = (const float*)d_in[4 + 2 * l]; }
    const int* src = ei;
    const int* dst = ei + E;
    (void)in_sizes; (void)n_in; (void)out_size;

    uintptr_t base = (uintptr_t)d_ws;
    uintptr_t cur = base;
    auto alloc = [&](size_t bytes) -> char* {
        uintptr_t q = (cur + 255) & ~(uintptr_t)255;
        cur = q + bytes;
        return (char*)q;
    };
    float* deg    = (float*)alloc((size_t)N * 4);
    float* dis    = (float*)alloc((size_t)N * 4);
    int*   rowptr = (int*)alloc((size_t)(N + 1) * 4);
    int*   cursor = (int*)alloc((size_t)N * 4);
    int*   csr_s  = (int*)alloc((size_t)E * 4);
    float* csr_n  = (float*)alloc((size_t)E * 4);
    float* Zb     = (float*)alloc((size_t)(K + 1) * N * 4);  // [21, N] hop-major
    float* ya     = (float*)alloc((size_t)N * 4);
    float* yb     = (float*)alloc((size_t)N * 4);
    float* h1     = (float*)alloc((size_t)N * 60 * 4);
    float* h2     = (float*)alloc((size_t)N * 100 * 4);
    float* h3     = (float*)alloc((size_t)N * 200 * 4);
    float* h4     = (float*)alloc((size_t)N * 80 * 4);
    float* Ra     = (float*)alloc((size_t)N * 80 * 4);
    float* Rb     = (float*)alloc((size_t)N * 80 * 4);
    float* W4t    = (float*)alloc((size_t)200 * 1680 * 4);

    // adaptive hop-batch arena from whatever workspace actually remains
    size_t used = (size_t)(cur - base);
    size_t avail = (ws_size > used + (1 << 20)) ? (ws_size - used - (1 << 20)) : 0;
    size_t cap = (size_t)N * 20 * 60 * 4;           // 240 MB covers H=20 at C=60
    size_t arena_bytes = avail < cap ? avail : cap;
    float* Sb = (float*)alloc(arena_bytes);
    auto clampH = [&](int Cin, int hi) {
        long h = (long)(arena_bytes / ((size_t)N * Cin * 4));
        if (h < 1) h = 1;
        if (h > hi) h = hi;
        return (int)h;
    };
    const int H2 = clampH(60, K);    // L2 stack width 60
    const int H3 = clampH(100, K);   // L3 stack width 100
    const int B4 = clampH(80, K + 1); // L4 Z-batch width 80

    // ---- CSR build
    hipMemsetAsync(deg, 0, (size_t)N * 4, stream);
    hipMemsetAsync(cursor, 0, (size_t)N * 4, stream);
    deg_count_kernel<<<(E + 255) / 256, 256, 0, stream>>>(src, dst, ew, deg, cursor, E);
    dis_kernel<<<(N + 255) / 256, 256, 0, stream>>>(deg, dis, N);
    scan_kernel<<<1, 1024, 0, stream>>>(cursor, rowptr, N);
    scatter_kernel<<<(E + 255) / 256, 256, 0, stream>>>(src, dst, ew, dis, cursor, csr_s, csr_n, E);

    const int PB = (N + 63) / 64;
    const int WB = (N + 3) / 4;
    const int GMX = (N + BM - 1) / BM;

    // ---- Layer 1 (1 -> 60): width-1 chain into Zb, one GEMM K=21
    hipMemcpyAsync(Zb, x, (size_t)N * 4, hipMemcpyDeviceToDevice, stream);
    for (int k = 1; k <= K; k++)
        prop1<<<PB, 256, 0, stream>>>(Zb + (size_t)(k - 1) * N, nullptr, Zb + (size_t)k * N,
                                      rowptr, csr_s, csr_n, N, 0);
    gemm2<<<dim3(GMX, 1), 256, 0, stream>>>(Zb, 1, N, Wl[0], 60, 1, bl[0],
                                            h1, 60, 1, N, K + 1, 60, GF_BIAS | GF_RELU, 60);

    // ---- middle layers: hop-batched forward (stack H hops, one long-K GEMM per batch)
    auto middle = [&](const float* Wt, const float* bt, int Cin, int Cout, int Hmax,
                      const float* Xin, float* Out,
                      void (*prop)(const float*, int, const float*, int, float*, int,
                                   const int*, const int*, const float*, int),
                      int gy) {
        gemm2<<<dim3(GMX, gy), 256, 0, stream>>>(Xin, Cin, 1, Wt, Cout, 1, bt,
                                                 Out, Cout, 1, N, Cin, Cout, GF_BIAS, Cout);
        int rowstr = Hmax * Cin;
        int done = 0;
        const float* prevp = Xin; int prevstr = Cin;
        while (done < K) {
            int H = (K - done < Hmax) ? (K - done) : Hmax;
            for (int j = 0; j < H; j++) {
                float* dstp = Sb + j * Cin;
                prop<<<WB, 256, 0, stream>>>(prevp, prevstr, nullptr, 0, dstp, rowstr,
                                             rowptr, csr_s, csr_n, N);
                prevp = dstp; prevstr = rowstr;
            }
            bool last = (done + H == K);
            gemm2<<<dim3(GMX, gy), 256, 0, stream>>>(Sb, rowstr, 1,
                Wt + (size_t)(1 + done) * Cin * Cout, Cout, 1, nullptr,
                Out, Cout, 1, N, H * Cin, Cout, GF_ACC | (last ? GF_RELU : 0), 0);
            done += H;
        }
    };
    middle(Wl[1], bl[1], 60, 100, H2, h1, h2, propw<15, 4, false, false>, 2);
    middle(Wl[2], bl[2], 100, 200, H3, h2, h3, propw<25, 2, false, false>, 4);

    // ---- Layer 4 (200 -> 80): batched Z pre-GEMM + Horner in width-80
    w4t_kernel<<<(336000 + 255) / 256, 256, 0, stream>>>(Wl[3], W4t, 336000);
    {
        int rowstr4 = B4 * 80;
        const float* curR = nullptr; int curstr = 0;
        int k_hi = K;
        while (k_hi >= 0) {
            int k_lo = k_hi - B4 + 1; if (k_lo < 0) k_lo = 0;
            int nb = k_hi - k_lo + 1;
            int gy = (nb * 80 + BN - 1) / BN;
            gemm2<<<dim3(GMX, gy), 256, 0, stream>>>(h3, 200, 1, W4t + (size_t)k_lo * 80, 1680, 1,
                bl[3], Sb, rowstr4, 1, N, 200, nb * 80,
                (k_lo == 0) ? GF_BIAS : 0, 80);
            int kstart;
            if (k_hi == K) { curR = Sb + (size_t)(K - k_lo) * 80; curstr = rowstr4; kstart = K - 1; }
            else kstart = k_hi;
            for (int k = kstart; k >= k_lo; k--) {
                const float* Zp = Sb + (size_t)(k - k_lo) * 80;
                if (k == 0) {
                    propw<20, 3, true, true><<<WB, 256, 0, stream>>>(curR, curstr, Zp, rowstr4,
                        h4, 80, rowptr, csr_s, csr_n, N);
                } else {
                    float* o = (k & 1) ? Ra : Rb;
                    propw<20, 3, true, false><<<WB, 256, 0, stream>>>(curR, curstr, Zp, rowstr4,
                        o, 80, rowptr, csr_s, csr_n, N);
                    curR = o; curstr = 80;
                }
            }
            k_hi = k_lo - 1;
        }
    }

    // ---- Layer 5 (80 -> 1): Z5 [21, N] col-major, Horner width-1 with sigmoid
    gemm2<<<dim3(GMX, 1), 256, 0, stream>>>(h4, 80, 1, Wl[4], 1, 80, bl[4],
                                            Zb, 1, N, N, 80, K + 1, GF_BIAS, 1);
    const float* cur5 = Zb + (size_t)K * N;
    float* outp = (float*)d_out;
    for (int k = K - 1; k >= 0; k--) {
        float* o = (k == 0) ? outp : ((k & 1) ? ya : yb);
        prop1<<<PB, 256, 0, stream>>>(cur5, Zb + (size_t)k * N, o,
                                      rowptr, csr_s, csr_n, N, (k == 0) ? 1 : 0);
        cur5 = o;
    }
}